// Round 8
// baseline (254.134 us; speedup 1.0000x reference)
//
#include <hip/hip_runtime.h>

#define GD(x,y) (((x)+(y)-1)/(y))

#define SH   10                // coarse: rows per bucket = 1024
#define BPR  (1 << SH)
#define SH2  7                 // fine: rows per sub-bucket = 128
#define SPB  (1 << (SH - SH2)) // sub-buckets per coarse bucket = 8
#define G1   1024              // blocks in hist/fill passes
#define BS   256

// P1: per-block coarse histogram (LDS), cnt layout bucket-major: cnt[b*G1 + blk]
__global__ void histb_k(const int* __restrict__ row, int* __restrict__ cnt,
                        int E, int NBK, int chunk){
    __shared__ int h[128];             // NBK <= 128 (N <= 131072 at SH=10)
    for (int i = threadIdx.x; i < NBK; i += BS) h[i] = 0;
    __syncthreads();
    int s = blockIdx.x * chunk, e = min(E, s + chunk);
    for (int i = s + threadIdx.x; i < e; i += BS)
        atomicAdd(&h[row[i] >> SH], 1);
    __syncthreads();
    for (int i = threadIdx.x; i < NBK; i += BS)
        cnt[(size_t)i * G1 + blockIdx.x] = h[i];
}

// ---- hierarchical exclusive scan over M ints ----
__global__ void scanA_k(const int* __restrict__ in, int* __restrict__ bsum, int M){
    __shared__ int lds[256];
    int t = threadIdx.x;
    int base = blockIdx.x * 1024 + t * 4;
    int s = 0;
    #pragma unroll
    for (int j = 0; j < 4; ++j) if (base + j < M) s += in[base + j];
    lds[t] = s; __syncthreads();
    for (int off = 128; off; off >>= 1){
        if (t < off) lds[t] += lds[t + off];
        __syncthreads();
    }
    if (t == 0) bsum[blockIdx.x] = lds[0];
}

// scanB + softmax(alpha) fused
__global__ void scanB_k(int* __restrict__ bsum, int NB,
                        const float* __restrict__ alpha, float* __restrict__ a, int na){
    __shared__ int lds[1024];
    int t = threadIdx.x;
    if (t == 0){
        float m = alpha[0];
        for (int i = 1; i < na; ++i) m = fmaxf(m, alpha[i]);
        float s = 0.f;
        for (int i = 0; i < na; ++i){ float e = expf(alpha[i] - m); a[i] = e; s += e; }
        float inv = 1.f / s;
        for (int i = 0; i < na; ++i) a[i] *= inv;
    }
    int v = (t < NB) ? bsum[t] : 0;
    lds[t] = v; __syncthreads();
    for (int off = 1; off < 1024; off <<= 1){
        int add = (t >= off) ? lds[t - off] : 0;
        __syncthreads();
        lds[t] += add;
        __syncthreads();
    }
    if (t < NB) bsum[t] = lds[t] - v;
}

__global__ void scanC_k(const int* __restrict__ in, const int* __restrict__ bsum,
                        int* __restrict__ outx, int M){
    __shared__ int lds[256];
    int t = threadIdx.x;
    int base = blockIdx.x * 1024 + t * 4;
    int d[4]; int s = 0;
    #pragma unroll
    for (int j = 0; j < 4; ++j){ d[j] = (base + j < M) ? in[base + j] : 0; s += d[j]; }
    lds[t] = s; __syncthreads();
    for (int off = 1; off < 256; off <<= 1){
        int add = (t >= off) ? lds[t - off] : 0;
        __syncthreads();
        lds[t] += add;
        __syncthreads();
    }
    int run = bsum[blockIdx.x] + lds[t] - s;
    #pragma unroll
    for (int j = 0; j < 4; ++j){
        int i = base + j;
        if (i < M){ outx[i] = run; run += d[j]; }
    }
}

// P3: scatter edges into coarse bucket order; pack {col | rloc10<<17, val}
__global__ void fill1_k(const int* __restrict__ row, const int* __restrict__ col,
                        const float* __restrict__ val, const int* __restrict__ base,
                        int2* __restrict__ sep, int E, int NBK, int chunk){
    __shared__ int cur[128];
    for (int i = threadIdx.x; i < NBK; i += BS)
        cur[i] = base[(size_t)i * G1 + blockIdx.x];
    __syncthreads();
    int s = blockIdx.x * chunk, e = min(E, s + chunk);
    for (int i = s + threadIdx.x; i < e; i += BS){
        int r = row[i];
        int b = r >> SH;
        int pos = atomicAdd(&cur[b], 1);
        int2 pk;
        pk.x = col[i] | ((r & (BPR - 1)) << 17);
        pk.y = __float_as_int(val[i]);
        sep[pos] = pk;
    }
}

// P4: within each coarse bucket, counting-sort edges into 8 sub-buckets.
// One block per coarse bucket; wave-ballot aggregation for LDS cursors;
// writes final pack {col | rloc7<<17, val} and sub-bucket boundaries sbptr.
__global__ void fill2_k(const int* __restrict__ bas, const int2* __restrict__ sep1,
                        int2* __restrict__ sep2, int* __restrict__ sbptr,
                        int NBK, int NSB, int E){
    __shared__ int h[SPB];
    __shared__ int excl[SPB + 1];
    __shared__ int curs[SPB];
    int b = blockIdx.x, t = threadIdx.x;
    int lane = t & 63;
    int s = bas[(size_t)b * G1];
    int e = (b + 1 < NBK) ? bas[(size_t)(b + 1) * G1] : E;
    if (t < SPB) h[t] = 0;
    __syncthreads();
    // phase 1: count sub-buckets (ballot-aggregated)
    for (int i = s + t; i < e; i += BS){
        int sb = (sep1[i].x >> 17) >> SH2;
        #pragma unroll
        for (int j = 0; j < SPB; ++j){
            unsigned long long m = __ballot(sb == j);
            if (m && lane == __ffsll(m) - 1) atomicAdd(&h[j], __popcll(m));
        }
    }
    __syncthreads();
    if (t == 0){
        int run = s;
        #pragma unroll
        for (int j = 0; j < SPB; ++j){ excl[j] = run; curs[j] = run; run += h[j]; }
        excl[SPB] = run;
    }
    __syncthreads();
    if (t < SPB) sbptr[b * SPB + t] = excl[t];
    if (b == NBK - 1 && t == 0) sbptr[NSB] = E;
    // phase 2: scatter into sub-bucket order
    for (int i = s + t; i < e; i += BS){
        int2 pk = sep1[i];
        int rl = pk.x >> 17;
        int sb = rl >> SH2;
        int pos = 0;
        #pragma unroll
        for (int j = 0; j < SPB; ++j){
            unsigned long long m = __ballot(sb == j);
            if (m){
                int leader = __ffsll(m) - 1;
                int base2 = 0;
                if (lane == leader) base2 = atomicAdd(&curs[j], __popcll(m));
                base2 = __shfl(base2, leader);
                if (sb == j)
                    pos = base2 + __popcll(m & ((1ull << lane) - 1));
            }
        }
        int2 o;
        o.x = (pk.x & 0x1FFFF) | ((rl & ((1 << SH2) - 1)) << 17);
        o.y = pk.y;
        sep2[pos] = o;
    }
}

// y[n] = emb[idx[n]] @ W (128->2); out[n] = b + a0*y[n]. Two rows per wave.
__global__ void proj_k(const float* __restrict__ emb, const int* __restrict__ idx,
                       const float* __restrict__ W, const float* __restrict__ b,
                       const float* __restrict__ a, float* __restrict__ y,
                       float* __restrict__ out, int N){
    int t = blockIdx.x * blockDim.x + threadIdx.x;
    int w = t >> 6;
    int lane = t & 63;
    int n = w * 2 + (lane >> 5);
    if (n >= N) return;
    int sl = lane & 31;
    float4 x = ((const float4*)(emb + (size_t)idx[n] * 128))[sl];
    int d0 = 4 * sl;
    float s0 = x.x * W[d0*2]   + x.y * W[d0*2+2] + x.z * W[d0*2+4] + x.w * W[d0*2+6];
    float s1 = x.x * W[d0*2+1] + x.y * W[d0*2+3] + x.z * W[d0*2+5] + x.w * W[d0*2+7];
    #pragma unroll
    for (int off = 16; off; off >>= 1){
        s0 += __shfl_down(s0, off, 32);
        s1 += __shfl_down(s1, off, 32);
    }
    if (sl == 0){
        float c = a[0];
        ((float2*)y)[n]   = make_float2(s0, s1);
        ((float2*)out)[n] = make_float2(b[0] + c * s0, b[1] + c * s1);
    }
}

// fine bucketed push SpMM: one block per 128-row sub-bucket, plane-split LDS
// accumulator, exclusive row ownership -> no global atomics.
__global__ void spmm7_k(const int* __restrict__ sbptr, const int2* __restrict__ sep2,
                        const float* __restrict__ y, float* __restrict__ nxt,
                        const float* __restrict__ a, int ai,
                        float* __restrict__ out, int N){
    __shared__ float accx[1 << SH2];
    __shared__ float accy[1 << SH2];
    int sb = blockIdx.x;
    int t = threadIdx.x;
    if (t < (1 << SH2)){ accx[t] = 0.f; accy[t] = 0.f; }
    __syncthreads();
    int s = sbptr[sb], e = sbptr[sb + 1];
    int i = s + t;
    for (; i + 3 * BS < e; i += 4 * BS){
        int2 p0 = sep2[i], p1 = sep2[i + BS], p2 = sep2[i + 2*BS], p3 = sep2[i + 3*BS];
        float2 m0 = ((const float2*)y)[p0.x & 0x1FFFF];
        float2 m1 = ((const float2*)y)[p1.x & 0x1FFFF];
        float2 m2 = ((const float2*)y)[p2.x & 0x1FFFF];
        float2 m3 = ((const float2*)y)[p3.x & 0x1FFFF];
        float v0 = __int_as_float(p0.y), v1 = __int_as_float(p1.y);
        float v2 = __int_as_float(p2.y), v3 = __int_as_float(p3.y);
        atomicAdd(&accx[p0.x >> 17], v0 * m0.x); atomicAdd(&accy[p0.x >> 17], v0 * m0.y);
        atomicAdd(&accx[p1.x >> 17], v1 * m1.x); atomicAdd(&accy[p1.x >> 17], v1 * m1.y);
        atomicAdd(&accx[p2.x >> 17], v2 * m2.x); atomicAdd(&accy[p2.x >> 17], v2 * m2.y);
        atomicAdd(&accx[p3.x >> 17], v3 * m3.x); atomicAdd(&accy[p3.x >> 17], v3 * m3.y);
    }
    for (; i < e; i += BS){
        int2 pk = sep2[i];
        float v = __int_as_float(pk.y);
        float2 m = ((const float2*)y)[pk.x & 0x1FFFF];
        atomicAdd(&accx[pk.x >> 17], v * m.x);
        atomicAdd(&accy[pk.x >> 17], v * m.y);
    }
    __syncthreads();
    if (t < (1 << SH2)){
        int n = (sb << SH2) + t;
        if (n < N){
            float2 z = make_float2(accx[t], accy[t]);
            ((float2*)nxt)[n] = z;
            float2 o = ((float2*)out)[n];
            o.x += a[ai] * z.x; o.y += a[ai] * z.y;
            ((float2*)out)[n] = o;
        }
    }
}

extern "C" void kernel_launch(void* const* d_in, const int* in_sizes, int n_in,
                              void* d_out, int out_size, void* d_ws, size_t ws_size,
                              hipStream_t stream) {
    const int*   node_idx = (const int*)  d_in[0];
    const int*   adj_row  = (const int*)  d_in[1];
    const int*   adj_col  = (const int*)  d_in[2];
    const float* adj_val  = (const float*)d_in[3];
    const float* emb      = (const float*)d_in[4];
    const float* alpha    = (const float*)d_in[5];
    const float* W        = (const float*)d_in[6];
    const float* b        = (const float*)d_in[7];
    float* out = (float*)d_out;

    const int N = in_sizes[0];      // 100000
    const int E = in_sizes[1];      // 1600000
    const int L = in_sizes[5] - 1;  // 3
    const int NBK = GD(N, BPR);     // 98 coarse buckets
    const int NSB = GD(N, 1 << SH2);// 782 sub-buckets
    const int M = NBK * G1;
    const int NBA = GD(M, 1024);
    const int chunk = GD(E, G1);

    // workspace
    char* w = (char*)d_ws;
    float* y    = (float*)w;  w += (size_t)N * 2 * 4;
    float* nxt  = (float*)w;  w += (size_t)N * 2 * 4;
    int2*  sep1 = (int2*)w;   w += (size_t)E * 8;
    int2*  sep2 = (int2*)w;   w += (size_t)E * 8;
    int*   cnt  = (int*)w;    w += (size_t)M * 4;
    int*   bas  = (int*)w;    w += (size_t)M * 4;
    int*   bsum = (int*)w;    w += 4096;
    int*   sbptr= (int*)w;    w += ((size_t)NSB + 16) * 4;
    float* a    = (float*)w;

    // one-time two-level bucket sort of edges (no global atomics)
    histb_k<<<G1, BS, 0, stream>>>(adj_row, cnt, E, NBK, chunk);
    scanA_k<<<NBA, 256, 0, stream>>>(cnt, bsum, M);
    scanB_k<<<1, 1024, 0, stream>>>(bsum, NBA, alpha, a, L + 1);
    scanC_k<<<NBA, 256, 0, stream>>>(cnt, bsum, bas, M);
    fill1_k<<<G1, BS, 0, stream>>>(adj_row, adj_col, adj_val, bas, sep1, E, NBK, chunk);
    fill2_k<<<NBK, BS, 0, stream>>>(bas, sep1, sep2, sbptr, NBK, NSB, E);

    // layer 0: project to 2 dims, init out
    proj_k<<<GD(N * 32, 256), 256, 0, stream>>>(emb, node_idx, W, b, a, y, out, N);

    // propagation layers: fine bucketed SpMM with fused out-accumulation
    for (int i = 0; i < L; ++i){
        spmm7_k<<<NSB, BS, 0, stream>>>(sbptr, sep2, y, nxt, a, i + 1, out, N);
        float* tmp = y; y = nxt; nxt = tmp;
    }
}

// Round 9
// 151.621 us; speedup vs baseline: 1.6761x; 1.6761x over previous
//
#include <hip/hip_runtime.h>

#define GD(x,y) (((x)+(y)-1)/(y))

#define SH   10                // rows per bucket = 1024
#define BPR  (1 << SH)
#define G1   256               // blocks in hist/fill passes (64-edge runs -> no RFO)
#define BS   256
#define KSPL 8                 // spmm splits per bucket

// P1: per-block coarse histogram (LDS), cnt layout bucket-major: cnt[b*G1 + blk]
__global__ void histb_k(const int* __restrict__ row, int* __restrict__ cnt,
                        int E, int NBK, int chunk){
    __shared__ int h[128];             // NBK <= 128
    for (int i = threadIdx.x; i < NBK; i += BS) h[i] = 0;
    __syncthreads();
    int s = blockIdx.x * chunk, e = min(E, s + chunk);
    for (int i = s + threadIdx.x; i < e; i += BS)
        atomicAdd(&h[row[i] >> SH], 1);
    __syncthreads();
    for (int i = threadIdx.x; i < NBK; i += BS)
        cnt[(size_t)i * G1 + blockIdx.x] = h[i];
}

// ---- hierarchical exclusive scan over M ints ----
__global__ void scanA_k(const int* __restrict__ in, int* __restrict__ bsum, int M){
    __shared__ int lds[256];
    int t = threadIdx.x;
    int base = blockIdx.x * 1024 + t * 4;
    int s = 0;
    #pragma unroll
    for (int j = 0; j < 4; ++j) if (base + j < M) s += in[base + j];
    lds[t] = s; __syncthreads();
    for (int off = 128; off; off >>= 1){
        if (t < off) lds[t] += lds[t + off];
        __syncthreads();
    }
    if (t == 0) bsum[blockIdx.x] = lds[0];
}

// scanB + softmax(alpha) fused
__global__ void scanB_k(int* __restrict__ bsum, int NB,
                        const float* __restrict__ alpha, float* __restrict__ a, int na){
    __shared__ int lds[1024];
    int t = threadIdx.x;
    if (t == 0){
        float m = alpha[0];
        for (int i = 1; i < na; ++i) m = fmaxf(m, alpha[i]);
        float s = 0.f;
        for (int i = 0; i < na; ++i){ float e = expf(alpha[i] - m); a[i] = e; s += e; }
        float inv = 1.f / s;
        for (int i = 0; i < na; ++i) a[i] *= inv;
    }
    int v = (t < NB) ? bsum[t] : 0;
    lds[t] = v; __syncthreads();
    for (int off = 1; off < 1024; off <<= 1){
        int add = (t >= off) ? lds[t - off] : 0;
        __syncthreads();
        lds[t] += add;
        __syncthreads();
    }
    if (t < NB) bsum[t] = lds[t] - v;
}

__global__ void scanC_k(const int* __restrict__ in, const int* __restrict__ bsum,
                        int* __restrict__ outx, int M){
    __shared__ int lds[256];
    int t = threadIdx.x;
    int base = blockIdx.x * 1024 + t * 4;
    int d[4]; int s = 0;
    #pragma unroll
    for (int j = 0; j < 4; ++j){ d[j] = (base + j < M) ? in[base + j] : 0; s += d[j]; }
    lds[t] = s; __syncthreads();
    for (int off = 1; off < 256; off <<= 1){
        int add = (t >= off) ? lds[t - off] : 0;
        __syncthreads();
        lds[t] += add;
        __syncthreads();
    }
    int run = bsum[blockIdx.x] + lds[t] - s;
    #pragma unroll
    for (int j = 0; j < 4; ++j){
        int i = base + j;
        if (i < M){ outx[i] = run; run += d[j]; }
    }
}

// P3: scatter edges into coarse bucket order; pack {col | rloc10<<17, val}
// 64-edge (512B) runs per (block,bucket) -> boundary-line sharing amortized.
__global__ void fill1_k(const int* __restrict__ row, const int* __restrict__ col,
                        const float* __restrict__ val, const int* __restrict__ base,
                        int2* __restrict__ sep, int E, int NBK, int chunk){
    __shared__ int cur[128];
    for (int i = threadIdx.x; i < NBK; i += BS)
        cur[i] = base[(size_t)i * G1 + blockIdx.x];
    __syncthreads();
    int s = blockIdx.x * chunk, e = min(E, s + chunk);
    for (int i = s + threadIdx.x; i < e; i += BS){
        int r = row[i];
        int b = r >> SH;
        int pos = atomicAdd(&cur[b], 1);
        int2 pk;
        pk.x = col[i] | ((r & (BPR - 1)) << 17);
        pk.y = __float_as_int(val[i]);
        sep[pos] = pk;
    }
}

// y[n] = emb[idx[n]] @ W (128->2); out[n] = b + a0*y[n]; zero both targets.
__global__ void proj_k(const float* __restrict__ emb, const int* __restrict__ idx,
                       const float* __restrict__ W, const float* __restrict__ b,
                       const float* __restrict__ a, float* __restrict__ y,
                       float* __restrict__ zb, float* __restrict__ zc,
                       float* __restrict__ out, int N){
    int t = blockIdx.x * blockDim.x + threadIdx.x;
    int w = t >> 6;
    int lane = t & 63;
    int n = w * 2 + (lane >> 5);
    if (n >= N) return;
    int sl = lane & 31;
    float4 x = ((const float4*)(emb + (size_t)idx[n] * 128))[sl];
    int d0 = 4 * sl;
    float s0 = x.x * W[d0*2]   + x.y * W[d0*2+2] + x.z * W[d0*2+4] + x.w * W[d0*2+6];
    float s1 = x.x * W[d0*2+1] + x.y * W[d0*2+3] + x.z * W[d0*2+5] + x.w * W[d0*2+7];
    #pragma unroll
    for (int off = 16; off; off >>= 1){
        s0 += __shfl_down(s0, off, 32);
        s1 += __shfl_down(s1, off, 32);
    }
    if (sl == 0){
        float c = a[0];
        ((float2*)y)[n]   = make_float2(s0, s1);
        ((float2*)zb)[n]  = make_float2(0.f, 0.f);
        ((float2*)zc)[n]  = make_float2(0.f, 0.f);
        ((float2*)out)[n] = make_float2(b[0] + c * s0, b[1] + c * s1);
    }
}

// split-bucket push SpMM: KSPL blocks per 1024-row bucket, private LDS
// accumulator, coalesced global-atomic writeback of partials.
// Also fuses out += a[ai] * partial. If !store, skips nxt accumulation.
__global__ void spmm_k(const int* __restrict__ bas, const int2* __restrict__ sep,
                       const float* __restrict__ yin, float* __restrict__ nxt,
                       const float* __restrict__ a, int ai, float* __restrict__ out,
                       int N, int NBK, int E, int store){
    __shared__ float accx[BPR];
    __shared__ float accy[BPR];
    int b  = blockIdx.x / KSPL;
    int sp = blockIdx.x % KSPL;
    int t  = threadIdx.x;
    for (int j = t; j < BPR; j += BS){ accx[j] = 0.f; accy[j] = 0.f; }
    __syncthreads();
    int s = bas[(size_t)b * G1];
    int e = (b + 1 < NBK) ? bas[(size_t)(b + 1) * G1] : E;
    int len = e - s, per = GD(len, KSPL);
    int cs = s + sp * per, ce = min(e, cs + per);
    int i = cs + t;
    for (; i + 3 * BS < ce; i += 4 * BS){
        int2 p0 = sep[i], p1 = sep[i + BS], p2 = sep[i + 2*BS], p3 = sep[i + 3*BS];
        float2 m0 = ((const float2*)yin)[p0.x & 0x1FFFF];
        float2 m1 = ((const float2*)yin)[p1.x & 0x1FFFF];
        float2 m2 = ((const float2*)yin)[p2.x & 0x1FFFF];
        float2 m3 = ((const float2*)yin)[p3.x & 0x1FFFF];
        float v0 = __int_as_float(p0.y), v1 = __int_as_float(p1.y);
        float v2 = __int_as_float(p2.y), v3 = __int_as_float(p3.y);
        atomicAdd(&accx[p0.x >> 17], v0 * m0.x); atomicAdd(&accy[p0.x >> 17], v0 * m0.y);
        atomicAdd(&accx[p1.x >> 17], v1 * m1.x); atomicAdd(&accy[p1.x >> 17], v1 * m1.y);
        atomicAdd(&accx[p2.x >> 17], v2 * m2.x); atomicAdd(&accy[p2.x >> 17], v2 * m2.y);
        atomicAdd(&accx[p3.x >> 17], v3 * m3.x); atomicAdd(&accy[p3.x >> 17], v3 * m3.y);
    }
    for (; i < ce; i += BS){
        int2 pk = sep[i];
        float v = __int_as_float(pk.y);
        float2 m = ((const float2*)yin)[pk.x & 0x1FFFF];
        atomicAdd(&accx[pk.x >> 17], v * m.x);
        atomicAdd(&accy[pk.x >> 17], v * m.y);
    }
    __syncthreads();
    float c = a[ai];
    for (int j = t; j < BPR; j += BS){
        int n = (b << SH) + j;
        if (n < N){
            float px = accx[j], py = accy[j];
            if (px != 0.f || py != 0.f){
                if (store){
                    atomicAdd(&nxt[2 * (size_t)n],     px);
                    atomicAdd(&nxt[2 * (size_t)n + 1], py);
                }
                atomicAdd(&out[2 * (size_t)n],     c * px);
                atomicAdd(&out[2 * (size_t)n + 1], c * py);
            }
        }
    }
}

extern "C" void kernel_launch(void* const* d_in, const int* in_sizes, int n_in,
                              void* d_out, int out_size, void* d_ws, size_t ws_size,
                              hipStream_t stream) {
    const int*   node_idx = (const int*)  d_in[0];
    const int*   adj_row  = (const int*)  d_in[1];
    const int*   adj_col  = (const int*)  d_in[2];
    const float* adj_val  = (const float*)d_in[3];
    const float* emb      = (const float*)d_in[4];
    const float* alpha    = (const float*)d_in[5];
    const float* W        = (const float*)d_in[6];
    const float* b        = (const float*)d_in[7];
    float* out = (float*)d_out;

    const int N = in_sizes[0];      // 100000
    const int E = in_sizes[1];      // 1600000
    const int L = in_sizes[5] - 1;  // 3
    const int NBK = GD(N, BPR);     // 98 buckets
    const int M = NBK * G1;         // 25088
    const int NBA = GD(M, 1024);    // 25
    const int chunk = GD(E, G1);

    // workspace
    char* w = (char*)d_ws;
    float* bufA = (float*)w;  w += (size_t)N * 2 * 4;   // y0 / layer-2 target
    float* bufB = (float*)w;  w += (size_t)N * 2 * 4;   // layer-1 target
    float* bufC = (float*)w;  w += (size_t)N * 2 * 4;   // layer-2 target
    int2*  sep  = (int2*)w;   w += (size_t)E * 8;
    int*   cnt  = (int*)w;    w += (size_t)M * 4;
    int*   bas  = (int*)w;    w += (size_t)M * 4;
    int*   bsum = (int*)w;    w += 4096;
    float* a    = (float*)w;

    // one-time bucket sort of edges into 1024-row buckets
    histb_k<<<G1, BS, 0, stream>>>(adj_row, cnt, E, NBK, chunk);
    scanA_k<<<NBA, 256, 0, stream>>>(cnt, bsum, M);
    scanB_k<<<1, 1024, 0, stream>>>(bsum, NBA, alpha, a, L + 1);
    scanC_k<<<NBA, 256, 0, stream>>>(cnt, bsum, bas, M);
    fill1_k<<<G1, BS, 0, stream>>>(adj_row, adj_col, adj_val, bas, sep, E, NBK, chunk);

    // layer 0: project to 2 dims, init out, zero scatter targets
    proj_k<<<GD(N * 32, 256), 256, 0, stream>>>(emb, node_idx, W, b, a,
                                                bufA, bufB, bufC, out, N);

    // propagation layers: split-bucket SpMM, fused out-accumulation
    float* src = bufA;
    float* dst = bufB;
    for (int i = 0; i < L; ++i){
        int store = (i < L - 1) ? 1 : 0;
        spmm_k<<<NBK * KSPL, BS, 0, stream>>>(bas, sep, src, dst, a, i + 1,
                                              out, N, NBK, E, store);
        src = dst;
        dst = (i == 0) ? bufC : bufA;   // layer2 -> bufC, layer3 -> unused
    }
}

// Round 10
// 138.122 us; speedup vs baseline: 1.8399x; 1.0977x over previous
//
#include <hip/hip_runtime.h>

#define GD(x,y) (((x)+(y)-1)/(y))

#define SH   10                // rows per bucket = 1024
#define BPR  (1 << SH)
#define G1   256               // blocks in hist/fill passes (64-edge runs -> no RFO)
#define BS   256
#define KSPL 8                 // spmm splits per bucket

// P1: per-block coarse histogram (LDS), cnt layout bucket-major: cnt[b*G1 + blk]
__global__ void histb_k(const int* __restrict__ row, int* __restrict__ cnt,
                        int E, int NBK, int chunk){
    __shared__ int h[128];             // NBK <= 128
    for (int i = threadIdx.x; i < NBK; i += BS) h[i] = 0;
    __syncthreads();
    int s = blockIdx.x * chunk, e = min(E, s + chunk);
    for (int i = s + threadIdx.x; i < e; i += BS)
        atomicAdd(&h[row[i] >> SH], 1);
    __syncthreads();
    for (int i = threadIdx.x; i < NBK; i += BS)
        cnt[(size_t)i * G1 + blockIdx.x] = h[i];
}

// ---- hierarchical exclusive scan over M ints ----
__global__ void scanA_k(const int* __restrict__ in, int* __restrict__ bsum, int M){
    __shared__ int lds[256];
    int t = threadIdx.x;
    int base = blockIdx.x * 1024 + t * 4;
    int s = 0;
    #pragma unroll
    for (int j = 0; j < 4; ++j) if (base + j < M) s += in[base + j];
    lds[t] = s; __syncthreads();
    for (int off = 128; off; off >>= 1){
        if (t < off) lds[t] += lds[t + off];
        __syncthreads();
    }
    if (t == 0) bsum[blockIdx.x] = lds[0];
}

// scanB + softmax(alpha) fused
__global__ void scanB_k(int* __restrict__ bsum, int NB,
                        const float* __restrict__ alpha, float* __restrict__ a, int na){
    __shared__ int lds[1024];
    int t = threadIdx.x;
    if (t == 0){
        float m = alpha[0];
        for (int i = 1; i < na; ++i) m = fmaxf(m, alpha[i]);
        float s = 0.f;
        for (int i = 0; i < na; ++i){ float e = expf(alpha[i] - m); a[i] = e; s += e; }
        float inv = 1.f / s;
        for (int i = 0; i < na; ++i) a[i] *= inv;
    }
    int v = (t < NB) ? bsum[t] : 0;
    lds[t] = v; __syncthreads();
    for (int off = 1; off < 1024; off <<= 1){
        int add = (t >= off) ? lds[t - off] : 0;
        __syncthreads();
        lds[t] += add;
        __syncthreads();
    }
    if (t < NB) bsum[t] = lds[t] - v;
}

__global__ void scanC_k(const int* __restrict__ in, const int* __restrict__ bsum,
                        int* __restrict__ outx, int M){
    __shared__ int lds[256];
    int t = threadIdx.x;
    int base = blockIdx.x * 1024 + t * 4;
    int d[4]; int s = 0;
    #pragma unroll
    for (int j = 0; j < 4; ++j){ d[j] = (base + j < M) ? in[base + j] : 0; s += d[j]; }
    lds[t] = s; __syncthreads();
    for (int off = 1; off < 256; off <<= 1){
        int add = (t >= off) ? lds[t - off] : 0;
        __syncthreads();
        lds[t] += add;
        __syncthreads();
    }
    int run = bsum[blockIdx.x] + lds[t] - s;
    #pragma unroll
    for (int j = 0; j < 4; ++j){
        int i = base + j;
        if (i < M){ outx[i] = run; run += d[j]; }
    }
}

// P3: scatter edges into coarse bucket order; pack {col | rloc10<<17, val}
__global__ void fill1_k(const int* __restrict__ row, const int* __restrict__ col,
                        const float* __restrict__ val, const int* __restrict__ base,
                        int2* __restrict__ sep, int E, int NBK, int chunk){
    __shared__ int cur[128];
    for (int i = threadIdx.x; i < NBK; i += BS)
        cur[i] = base[(size_t)i * G1 + blockIdx.x];
    __syncthreads();
    int s = blockIdx.x * chunk, e = min(E, s + chunk);
    for (int i = s + threadIdx.x; i < e; i += BS){
        int r = row[i];
        int b = r >> SH;
        int pos = atomicAdd(&cur[b], 1);
        int2 pk;
        pk.x = col[i] | ((r & (BPR - 1)) << 17);
        pk.y = __float_as_int(val[i]);
        sep[pos] = pk;
    }
}

// y[n] = emb[idx[n]] @ W (128->2); out[n] = b + a0*y[n]. Two rows per wave.
__global__ void proj_k(const float* __restrict__ emb, const int* __restrict__ idx,
                       const float* __restrict__ W, const float* __restrict__ b,
                       const float* __restrict__ a, float* __restrict__ y,
                       float* __restrict__ out, int N){
    int t = blockIdx.x * blockDim.x + threadIdx.x;
    int w = t >> 6;
    int lane = t & 63;
    int n = w * 2 + (lane >> 5);
    if (n >= N) return;
    int sl = lane & 31;
    float4 x = ((const float4*)(emb + (size_t)idx[n] * 128))[sl];
    int d0 = 4 * sl;
    float s0 = x.x * W[d0*2]   + x.y * W[d0*2+2] + x.z * W[d0*2+4] + x.w * W[d0*2+6];
    float s1 = x.x * W[d0*2+1] + x.y * W[d0*2+3] + x.z * W[d0*2+5] + x.w * W[d0*2+7];
    #pragma unroll
    for (int off = 16; off; off >>= 1){
        s0 += __shfl_down(s0, off, 32);
        s1 += __shfl_down(s1, off, 32);
    }
    if (sl == 0){
        float c = a[0];
        ((float2*)y)[n]   = make_float2(s0, s1);
        ((float2*)out)[n] = make_float2(b[0] + c * s0, b[1] + c * s1);
    }
}

// split-bucket push SpMM: KSPL blocks per 1024-row bucket, private LDS
// accumulator, NON-ATOMIC contiguous streaming writeback of partials.
__global__ void spmm_k(const int* __restrict__ bas, const int2* __restrict__ sep,
                       const float* __restrict__ yin, float* __restrict__ partial,
                       int NBK, int E){
    __shared__ float accx[BPR];
    __shared__ float accy[BPR];
    int b  = blockIdx.x / KSPL;
    int sp = blockIdx.x % KSPL;
    int t  = threadIdx.x;
    for (int j = t; j < BPR; j += BS){ accx[j] = 0.f; accy[j] = 0.f; }
    __syncthreads();
    int s = bas[(size_t)b * G1];
    int e = (b + 1 < NBK) ? bas[(size_t)(b + 1) * G1] : E;
    int len = e - s, per = GD(len, KSPL);
    int cs = s + sp * per, ce = min(e, cs + per);
    int i = cs + t;
    for (; i + 3 * BS < ce; i += 4 * BS){
        int2 p0 = sep[i], p1 = sep[i + BS], p2 = sep[i + 2*BS], p3 = sep[i + 3*BS];
        float2 m0 = ((const float2*)yin)[p0.x & 0x1FFFF];
        float2 m1 = ((const float2*)yin)[p1.x & 0x1FFFF];
        float2 m2 = ((const float2*)yin)[p2.x & 0x1FFFF];
        float2 m3 = ((const float2*)yin)[p3.x & 0x1FFFF];
        float v0 = __int_as_float(p0.y), v1 = __int_as_float(p1.y);
        float v2 = __int_as_float(p2.y), v3 = __int_as_float(p3.y);
        atomicAdd(&accx[p0.x >> 17], v0 * m0.x); atomicAdd(&accy[p0.x >> 17], v0 * m0.y);
        atomicAdd(&accx[p1.x >> 17], v1 * m1.x); atomicAdd(&accy[p1.x >> 17], v1 * m1.y);
        atomicAdd(&accx[p2.x >> 17], v2 * m2.x); atomicAdd(&accy[p2.x >> 17], v2 * m2.y);
        atomicAdd(&accx[p3.x >> 17], v3 * m3.x); atomicAdd(&accy[p3.x >> 17], v3 * m3.y);
    }
    for (; i < ce; i += BS){
        int2 pk = sep[i];
        float v = __int_as_float(pk.y);
        float2 m = ((const float2*)yin)[pk.x & 0x1FFFF];
        atomicAdd(&accx[pk.x >> 17], v * m.x);
        atomicAdd(&accy[pk.x >> 17], v * m.y);
    }
    __syncthreads();
    float2* dst = (float2*)partial + (size_t)(b * KSPL + sp) * BPR;
    for (int j = t; j < BPR; j += BS)
        dst[j] = make_float2(accx[j], accy[j]);
}

// combine partials: y_next[n] = sum_sp partial[b,sp,j]; out[n] += a[ai]*y_next[n].
// One thread per row; no atomics (exclusive ownership).
__global__ void comb_k(const float* __restrict__ partial, const float* __restrict__ a,
                       int ai, float* __restrict__ ynext, float* __restrict__ out,
                       int N, int store){
    int n = blockIdx.x * blockDim.x + threadIdx.x;
    if (n >= N) return;
    int b = n >> SH, j = n & (BPR - 1);
    const float2* p = (const float2*)partial + (size_t)b * KSPL * BPR + j;
    float sx = 0.f, sy = 0.f;
    #pragma unroll
    for (int sp = 0; sp < KSPL; ++sp){
        float2 v = p[(size_t)sp * BPR];
        sx += v.x; sy += v.y;
    }
    if (store) ((float2*)ynext)[n] = make_float2(sx, sy);
    float c = a[ai];
    float2 o = ((float2*)out)[n];
    o.x += c * sx; o.y += c * sy;
    ((float2*)out)[n] = o;
}

extern "C" void kernel_launch(void* const* d_in, const int* in_sizes, int n_in,
                              void* d_out, int out_size, void* d_ws, size_t ws_size,
                              hipStream_t stream) {
    const int*   node_idx = (const int*)  d_in[0];
    const int*   adj_row  = (const int*)  d_in[1];
    const int*   adj_col  = (const int*)  d_in[2];
    const float* adj_val  = (const float*)d_in[3];
    const float* emb      = (const float*)d_in[4];
    const float* alpha    = (const float*)d_in[5];
    const float* W        = (const float*)d_in[6];
    const float* b        = (const float*)d_in[7];
    float* out = (float*)d_out;

    const int N = in_sizes[0];      // 100000
    const int E = in_sizes[1];      // 1600000
    const int L = in_sizes[5] - 1;  // 3
    const int NBK = GD(N, BPR);     // 98 buckets
    const int M = NBK * G1;         // 25088
    const int NBA = GD(M, 1024);    // 25
    const int chunk = GD(E, G1);

    // workspace
    char* w = (char*)d_ws;
    float* yA     = (float*)w;  w += (size_t)N * 2 * 4;
    float* yB     = (float*)w;  w += (size_t)N * 2 * 4;
    float* partial= (float*)w;  w += (size_t)NBK * KSPL * BPR * 2 * 4;  // 6.4 MB
    int2*  sep    = (int2*)w;   w += (size_t)E * 8;
    int*   cnt    = (int*)w;    w += (size_t)M * 4;
    int*   bas    = (int*)w;    w += (size_t)M * 4;
    int*   bsum   = (int*)w;    w += 4096;
    float* a      = (float*)w;

    // one-time bucket sort of edges into 1024-row buckets
    histb_k<<<G1, BS, 0, stream>>>(adj_row, cnt, E, NBK, chunk);
    scanA_k<<<NBA, 256, 0, stream>>>(cnt, bsum, M);
    scanB_k<<<1, 1024, 0, stream>>>(bsum, NBA, alpha, a, L + 1);
    scanC_k<<<NBA, 256, 0, stream>>>(cnt, bsum, bas, M);
    fill1_k<<<G1, BS, 0, stream>>>(adj_row, adj_col, adj_val, bas, sep, E, NBK, chunk);

    // layer 0: project to 2 dims, init out
    proj_k<<<GD(N * 32, 256), 256, 0, stream>>>(emb, node_idx, W, b, a, yA, out, N);

    // propagation layers: split-bucket SpMM -> non-atomic combine
    float* ysrc = yA;
    float* ydst = yB;
    for (int i = 0; i < L; ++i){
        spmm_k<<<NBK * KSPL, BS, 0, stream>>>(bas, sep, ysrc, partial, NBK, E);
        comb_k<<<GD(N, 256), 256, 0, stream>>>(partial, a, i + 1, ydst, out,
                                               N, (i < L - 1) ? 1 : 0);
        float* tmp = ysrc; ysrc = ydst; ydst = tmp;
    }
}

// Round 11
// 128.561 us; speedup vs baseline: 1.9768x; 1.0744x over previous
//
#include <hip/hip_runtime.h>

#define GD(x,y) (((x)+(y)-1)/(y))

#define SH    10               // rows per bucket = 1024
#define BPR   (1 << SH)
#define G1    256              // blocks in fill pass (64-edge runs -> no RFO)
#define BS    256
#define KSPL  24               // spmm splits per bucket
#define CAPSH 15               // slot capacity per bucket = 32768 edges
#define CAP   (1 << CAPSH)

static __device__ __forceinline__ float2 ntload2(const float2* p){
    unsigned long long u = __builtin_nontemporal_load((const unsigned long long*)p);
    return *(float2*)&u;
}
static __device__ __forceinline__ void ntstore2(float2* p, float2 v){
    __builtin_nontemporal_store(*(unsigned long long*)&v, (unsigned long long*)p);
}

// init: cursor[b] = b*CAP (slot bases) + softmax(alpha)
__global__ void init_k(int* __restrict__ cursor, int NBK,
                       const float* __restrict__ alpha, float* __restrict__ a, int na){
    int t = threadIdx.x;
    if (t < NBK) cursor[t] = t << CAPSH;
    if (t == 0){
        float m = alpha[0];
        for (int i = 1; i < na; ++i) m = fmaxf(m, alpha[i]);
        float s = 0.f;
        for (int i = 0; i < na; ++i){ float e = expf(alpha[i] - m); a[i] = e; s += e; }
        float inv = 1.f / s;
        for (int i = 0; i < na; ++i) a[i] *= inv;
    }
}

// fused count + atomic-reserve + scatter into fixed bucket slots.
// pack {col | rloc10<<17, val}
__global__ void fillf_k(const int* __restrict__ row, const int* __restrict__ col,
                        const float* __restrict__ val, int* __restrict__ cursor,
                        int2* __restrict__ sep, int E, int NBK, int chunk){
    __shared__ int h[128];
    __shared__ int curb[128];
    int t = threadIdx.x;
    for (int i = t; i < NBK; i += BS) h[i] = 0;
    __syncthreads();
    int s = blockIdx.x * chunk, e = min(E, s + chunk);
    // pass 1: count this block's bucket loads
    for (int i = s + t; i < e; i += BS)
        atomicAdd(&h[row[i] >> SH], 1);
    __syncthreads();
    // reserve contiguous runs in each bucket slot
    if (t < NBK) curb[t] = (h[t] > 0) ? atomicAdd(&cursor[t], h[t]) : 0;
    __syncthreads();
    // pass 2: scatter (64-edge average runs -> full-line writes)
    for (int i = s + t; i < e; i += BS){
        int r = row[i];
        int b = r >> SH;
        int pos = atomicAdd(&curb[b], 1);
        int2 pk;
        pk.x = col[i] | ((r & (BPR - 1)) << 17);
        pk.y = __float_as_int(val[i]);
        sep[pos] = pk;
    }
}

// y[n] = emb[idx[n]] @ W (128->2); out[n] = b + a0*y[n]. Two rows per wave.
__global__ void proj_k(const float* __restrict__ emb, const int* __restrict__ idx,
                       const float* __restrict__ W, const float* __restrict__ b,
                       const float* __restrict__ a, float* __restrict__ y,
                       float* __restrict__ out, int N){
    int t = blockIdx.x * blockDim.x + threadIdx.x;
    int w = t >> 6;
    int lane = t & 63;
    int n = w * 2 + (lane >> 5);
    if (n >= N) return;
    int sl = lane & 31;
    float4 x = ((const float4*)(emb + (size_t)idx[n] * 128))[sl];
    int d0 = 4 * sl;
    float s0 = x.x * W[d0*2]   + x.y * W[d0*2+2] + x.z * W[d0*2+4] + x.w * W[d0*2+6];
    float s1 = x.x * W[d0*2+1] + x.y * W[d0*2+3] + x.z * W[d0*2+5] + x.w * W[d0*2+7];
    #pragma unroll
    for (int off = 16; off; off >>= 1){
        s0 += __shfl_down(s0, off, 32);
        s1 += __shfl_down(s1, off, 32);
    }
    if (sl == 0){
        float c = a[0];
        ((float2*)y)[n]   = make_float2(s0, s1);
        ((float2*)out)[n] = make_float2(b[0] + c * s0, b[1] + c * s1);
    }
}

// split-bucket push SpMM: KSPL blocks per 1024-row bucket, private LDS
// accumulator, nontemporal contiguous writeback of partials.
__global__ void spmm_k(const int* __restrict__ cursor, const int2* __restrict__ sep,
                       const float* __restrict__ yin, float* __restrict__ partial,
                       int NBK){
    __shared__ float accx[BPR];
    __shared__ float accy[BPR];
    int b  = blockIdx.x / KSPL;
    int sp = blockIdx.x % KSPL;
    int t  = threadIdx.x;
    for (int j = t; j < BPR; j += BS){ accx[j] = 0.f; accy[j] = 0.f; }
    __syncthreads();
    int s = b << CAPSH;
    int e = cursor[b];
    int len = e - s, per = GD(len, KSPL);
    int cs = s + sp * per, ce = min(e, cs + per);
    int i = cs + t;
    for (; i + 3 * BS < ce; i += 4 * BS){
        int2 p0 = sep[i], p1 = sep[i + BS], p2 = sep[i + 2*BS], p3 = sep[i + 3*BS];
        float2 m0 = ((const float2*)yin)[p0.x & 0x1FFFF];
        float2 m1 = ((const float2*)yin)[p1.x & 0x1FFFF];
        float2 m2 = ((const float2*)yin)[p2.x & 0x1FFFF];
        float2 m3 = ((const float2*)yin)[p3.x & 0x1FFFF];
        float v0 = __int_as_float(p0.y), v1 = __int_as_float(p1.y);
        float v2 = __int_as_float(p2.y), v3 = __int_as_float(p3.y);
        atomicAdd(&accx[p0.x >> 17], v0 * m0.x); atomicAdd(&accy[p0.x >> 17], v0 * m0.y);
        atomicAdd(&accx[p1.x >> 17], v1 * m1.x); atomicAdd(&accy[p1.x >> 17], v1 * m1.y);
        atomicAdd(&accx[p2.x >> 17], v2 * m2.x); atomicAdd(&accy[p2.x >> 17], v2 * m2.y);
        atomicAdd(&accx[p3.x >> 17], v3 * m3.x); atomicAdd(&accy[p3.x >> 17], v3 * m3.y);
    }
    for (; i < ce; i += BS){
        int2 pk = sep[i];
        float v = __int_as_float(pk.y);
        float2 m = ((const float2*)yin)[pk.x & 0x1FFFF];
        atomicAdd(&accx[pk.x >> 17], v * m.x);
        atomicAdd(&accy[pk.x >> 17], v * m.y);
    }
    __syncthreads();
    float2* dst = (float2*)partial + (size_t)(b * KSPL + sp) * BPR;
    for (int j = t; j < BPR; j += BS)
        ntstore2(&dst[j], make_float2(accx[j], accy[j]));
}

// combine partials: y_next[n] = sum_sp partial[b,sp,j]; out[n] += a[ai]*y_next.
__global__ void comb_k(const float* __restrict__ partial, const float* __restrict__ a,
                       int ai, float* __restrict__ ynext, float* __restrict__ out,
                       int N, int store){
    int n = blockIdx.x * blockDim.x + threadIdx.x;
    if (n >= N) return;
    int b = n >> SH, j = n & (BPR - 1);
    const float2* p = (const float2*)partial + (size_t)b * KSPL * BPR + j;
    float sx = 0.f, sy = 0.f;
    #pragma unroll
    for (int sp = 0; sp < KSPL; ++sp){
        float2 v = ntload2(&p[(size_t)sp * BPR]);
        sx += v.x; sy += v.y;
    }
    if (store) ((float2*)ynext)[n] = make_float2(sx, sy);
    float c = a[ai];
    float2 o = ((float2*)out)[n];
    o.x += c * sx; o.y += c * sy;
    ((float2*)out)[n] = o;
}

extern "C" void kernel_launch(void* const* d_in, const int* in_sizes, int n_in,
                              void* d_out, int out_size, void* d_ws, size_t ws_size,
                              hipStream_t stream) {
    const int*   node_idx = (const int*)  d_in[0];
    const int*   adj_row  = (const int*)  d_in[1];
    const int*   adj_col  = (const int*)  d_in[2];
    const float* adj_val  = (const float*)d_in[3];
    const float* emb      = (const float*)d_in[4];
    const float* alpha    = (const float*)d_in[5];
    const float* W        = (const float*)d_in[6];
    const float* b        = (const float*)d_in[7];
    float* out = (float*)d_out;

    const int N = in_sizes[0];      // 100000
    const int E = in_sizes[1];      // 1600000
    const int L = in_sizes[5] - 1;  // 3
    const int NBK = GD(N, BPR);     // 98 buckets
    const int chunk = GD(E, G1);

    // workspace
    char* w = (char*)d_ws;
    float* yA     = (float*)w;  w += (size_t)N * 2 * 4;
    float* yB     = (float*)w;  w += (size_t)N * 2 * 4;
    float* partial= (float*)w;  w += (size_t)NBK * KSPL * BPR * 2 * 4;  // 19.3 MB
    int2*  sep    = (int2*)w;   w += (size_t)NBK * CAP * 8;             // 25.7 MB
    int*   cursor = (int*)w;    w += 1024;
    float* a      = (float*)w;

    // sort edges into fixed-capacity 1024-row bucket slots (single fused pass)
    init_k<<<1, 128, 0, stream>>>(cursor, NBK, alpha, a, L + 1);
    fillf_k<<<G1, BS, 0, stream>>>(adj_row, adj_col, adj_val, cursor, sep, E, NBK, chunk);

    // layer 0: project to 2 dims, init out
    proj_k<<<GD(N * 32, 256), 256, 0, stream>>>(emb, node_idx, W, b, a, yA, out, N);

    // propagation layers: split-bucket SpMM -> non-atomic combine
    float* ysrc = yA;
    float* ydst = yB;
    for (int i = 0; i < L; ++i){
        spmm_k<<<NBK * KSPL, BS, 0, stream>>>(cursor, sep, ysrc, partial, NBK);
        comb_k<<<GD(N, 256), 256, 0, stream>>>(partial, a, i + 1, ydst, out,
                                               N, (i < L - 1) ? 1 : 0);
        float* tmp = ysrc; ysrc = ydst; ydst = tmp;
    }
}

// Round 12
// 125.831 us; speedup vs baseline: 2.0197x; 1.0217x over previous
//
#include <hip/hip_runtime.h>

#define GD(x,y) (((x)+(y)-1)/(y))

#define SH    10               // rows per bucket = 1024
#define BPR   (1 << SH)
#define BS    256
#define KSPL  24               // spmm splits per bucket
#define CAPSH 15               // slot capacity per bucket = 32768 edges
#define CAP   (1 << CAPSH)
#define CHUNK 2048             // edges per fill block (16KB staged LDS)

static __device__ __forceinline__ float2 ntload2(const float2* p){
    unsigned long long u = __builtin_nontemporal_load((const unsigned long long*)p);
    return *(float2*)&u;
}
static __device__ __forceinline__ void ntstore2(float2* p, float2 v){
    __builtin_nontemporal_store(*(unsigned long long*)&v, (unsigned long long*)p);
}

// init: cursor[b] = b*CAP (slot bases) + softmax(alpha)
__global__ void init_k(int* __restrict__ cursor, int NBK,
                       const float* __restrict__ alpha, float* __restrict__ a, int na){
    int t = threadIdx.x;
    if (t < NBK) cursor[t] = t << CAPSH;
    if (t == 0){
        float m = alpha[0];
        for (int i = 1; i < na; ++i) m = fmaxf(m, alpha[i]);
        float s = 0.f;
        for (int i = 0; i < na; ++i){ float e = expf(alpha[i] - m); a[i] = e; s += e; }
        float inv = 1.f / s;
        for (int i = 0; i < na; ++i) a[i] *= inv;
    }
}

// fused count + reserve + LDS-staged sort + coalesced stream-out.
// pack {col | rloc10<<17, val}
__global__ void fillf_k(const int* __restrict__ row, const int* __restrict__ col,
                        const float* __restrict__ val, int* __restrict__ cursor,
                        int2* __restrict__ sep, int E, int NBK){
    __shared__ int2 staged[CHUNK];          // 16 KB
    __shared__ unsigned char bid[CHUNK];    // 2 KB
    __shared__ int h[128], lstart[128], gbase[128], lcur[128];
    int t = threadIdx.x;
    int s = blockIdx.x * CHUNK;
    int e = min(E, s + CHUNK);
    int cnt = e - s;
    for (int i = t; i < NBK; i += BS) h[i] = 0;
    __syncthreads();
    // pass 1: count (4-wide)
    for (int base = s + t * 4; base < e; base += BS * 4){
        if (base + 3 < e){
            int4 r4 = *(const int4*)(row + base);
            atomicAdd(&h[r4.x >> SH], 1);
            atomicAdd(&h[r4.y >> SH], 1);
            atomicAdd(&h[r4.z >> SH], 1);
            atomicAdd(&h[r4.w >> SH], 1);
        } else {
            for (int j = 0; j < 4 && base + j < e; ++j)
                atomicAdd(&h[row[base + j] >> SH], 1);
        }
    }
    __syncthreads();
    // local exclusive prefix (serial over <=98 bins)
    if (t == 0){
        int run = 0;
        for (int i = 0; i < NBK; ++i){ lstart[i] = run; run += h[i]; }
    }
    __syncthreads();
    // reserve contiguous global runs
    if (t < NBK){
        lcur[t] = lstart[t];
        gbase[t] = (h[t] > 0) ? atomicAdd(&cursor[t], h[t]) : 0;
    }
    __syncthreads();
    // pass 2: scatter into LDS (bucket-sorted within block)
    for (int base = s + t * 4; base < e; base += BS * 4){
        int  r[4]; int c[4]; float v[4];
        int  m = min(4, e - base);
        if (m == 4){
            int4 r4 = *(const int4*)(row + base);
            int4 c4 = *(const int4*)(col + base);
            float4 v4 = *(const float4*)(val + base);
            r[0]=r4.x; r[1]=r4.y; r[2]=r4.z; r[3]=r4.w;
            c[0]=c4.x; c[1]=c4.y; c[2]=c4.z; c[3]=c4.w;
            v[0]=v4.x; v[1]=v4.y; v[2]=v4.z; v[3]=v4.w;
        } else {
            for (int j = 0; j < m; ++j){ r[j]=row[base+j]; c[j]=col[base+j]; v[j]=val[base+j]; }
        }
        for (int j = 0; j < m; ++j){
            int b = r[j] >> SH;
            int lp = atomicAdd(&lcur[b], 1);
            int2 pk;
            pk.x = c[j] | ((r[j] & (BPR - 1)) << 17);
            pk.y = __float_as_int(v[j]);
            staged[lp] = pk;
            bid[lp] = (unsigned char)b;
        }
    }
    __syncthreads();
    // stream out: consecutive idx -> consecutive global positions per run
    for (int idx = t; idx < cnt; idx += BS){
        int b = bid[idx];
        sep[gbase[b] + (idx - lstart[b])] = staged[idx];
    }
}

// y[n] = emb[idx[n]] @ W (128->2); out[n] = b + a0*y[n]. Two rows per wave.
__global__ void proj_k(const float* __restrict__ emb, const int* __restrict__ idx,
                       const float* __restrict__ W, const float* __restrict__ b,
                       const float* __restrict__ a, float* __restrict__ y,
                       float* __restrict__ out, int N){
    int t = blockIdx.x * blockDim.x + threadIdx.x;
    int w = t >> 6;
    int lane = t & 63;
    int n = w * 2 + (lane >> 5);
    if (n >= N) return;
    int sl = lane & 31;
    float4 x = ((const float4*)(emb + (size_t)idx[n] * 128))[sl];
    int d0 = 4 * sl;
    float s0 = x.x * W[d0*2]   + x.y * W[d0*2+2] + x.z * W[d0*2+4] + x.w * W[d0*2+6];
    float s1 = x.x * W[d0*2+1] + x.y * W[d0*2+3] + x.z * W[d0*2+5] + x.w * W[d0*2+7];
    #pragma unroll
    for (int off = 16; off; off >>= 1){
        s0 += __shfl_down(s0, off, 32);
        s1 += __shfl_down(s1, off, 32);
    }
    if (sl == 0){
        float c = a[0];
        ((float2*)y)[n]   = make_float2(s0, s1);
        ((float2*)out)[n] = make_float2(b[0] + c * s0, b[1] + c * s1);
    }
}

// split-bucket push SpMM: KSPL blocks per 1024-row bucket, private LDS
// accumulator, nontemporal contiguous writeback of partials.
__global__ void spmm_k(const int* __restrict__ cursor, const int2* __restrict__ sep,
                       const float* __restrict__ yin, float* __restrict__ partial,
                       int NBK){
    __shared__ float accx[BPR];
    __shared__ float accy[BPR];
    int b  = blockIdx.x / KSPL;
    int sp = blockIdx.x % KSPL;
    int t  = threadIdx.x;
    for (int j = t; j < BPR; j += BS){ accx[j] = 0.f; accy[j] = 0.f; }
    __syncthreads();
    int s = b << CAPSH;
    int e = cursor[b];
    int len = e - s, per = GD(len, KSPL);
    int cs = s + sp * per, ce = min(e, cs + per);
    int i = cs + t;
    for (; i + 3 * BS < ce; i += 4 * BS){
        int2 p0 = sep[i], p1 = sep[i + BS], p2 = sep[i + 2*BS], p3 = sep[i + 3*BS];
        float2 m0 = ((const float2*)yin)[p0.x & 0x1FFFF];
        float2 m1 = ((const float2*)yin)[p1.x & 0x1FFFF];
        float2 m2 = ((const float2*)yin)[p2.x & 0x1FFFF];
        float2 m3 = ((const float2*)yin)[p3.x & 0x1FFFF];
        float v0 = __int_as_float(p0.y), v1 = __int_as_float(p1.y);
        float v2 = __int_as_float(p2.y), v3 = __int_as_float(p3.y);
        atomicAdd(&accx[p0.x >> 17], v0 * m0.x); atomicAdd(&accy[p0.x >> 17], v0 * m0.y);
        atomicAdd(&accx[p1.x >> 17], v1 * m1.x); atomicAdd(&accy[p1.x >> 17], v1 * m1.y);
        atomicAdd(&accx[p2.x >> 17], v2 * m2.x); atomicAdd(&accy[p2.x >> 17], v2 * m2.y);
        atomicAdd(&accx[p3.x >> 17], v3 * m3.x); atomicAdd(&accy[p3.x >> 17], v3 * m3.y);
    }
    for (; i < ce; i += BS){
        int2 pk = sep[i];
        float v = __int_as_float(pk.y);
        float2 m = ((const float2*)yin)[pk.x & 0x1FFFF];
        atomicAdd(&accx[pk.x >> 17], v * m.x);
        atomicAdd(&accy[pk.x >> 17], v * m.y);
    }
    __syncthreads();
    float2* dst = (float2*)partial + (size_t)(b * KSPL + sp) * BPR;
    for (int j = t; j < BPR; j += BS)
        ntstore2(&dst[j], make_float2(accx[j], accy[j]));
}

// combine partials: y_next[n] = sum_sp partial[b,sp,j]; out[n] += a[ai]*y_next.
__global__ void comb_k(const float* __restrict__ partial, const float* __restrict__ a,
                       int ai, float* __restrict__ ynext, float* __restrict__ out,
                       int N, int store){
    int n = blockIdx.x * blockDim.x + threadIdx.x;
    if (n >= N) return;
    int b = n >> SH, j = n & (BPR - 1);
    const float2* p = (const float2*)partial + (size_t)b * KSPL * BPR + j;
    float sx = 0.f, sy = 0.f;
    #pragma unroll
    for (int sp = 0; sp < KSPL; ++sp){
        float2 v = ntload2(&p[(size_t)sp * BPR]);
        sx += v.x; sy += v.y;
    }
    if (store) ((float2*)ynext)[n] = make_float2(sx, sy);
    float c = a[ai];
    float2 o = ((float2*)out)[n];
    o.x += c * sx; o.y += c * sy;
    ((float2*)out)[n] = o;
}

extern "C" void kernel_launch(void* const* d_in, const int* in_sizes, int n_in,
                              void* d_out, int out_size, void* d_ws, size_t ws_size,
                              hipStream_t stream) {
    const int*   node_idx = (const int*)  d_in[0];
    const int*   adj_row  = (const int*)  d_in[1];
    const int*   adj_col  = (const int*)  d_in[2];
    const float* adj_val  = (const float*)d_in[3];
    const float* emb      = (const float*)d_in[4];
    const float* alpha    = (const float*)d_in[5];
    const float* W        = (const float*)d_in[6];
    const float* b        = (const float*)d_in[7];
    float* out = (float*)d_out;

    const int N = in_sizes[0];      // 100000
    const int E = in_sizes[1];      // 1600000
    const int L = in_sizes[5] - 1;  // 3
    const int NBK = GD(N, BPR);     // 98 buckets
    const int GF  = GD(E, CHUNK);   // 782 fill blocks

    // workspace
    char* w = (char*)d_ws;
    float* yA     = (float*)w;  w += (size_t)N * 2 * 4;
    float* yB     = (float*)w;  w += (size_t)N * 2 * 4;
    float* partial= (float*)w;  w += (size_t)NBK * KSPL * BPR * 2 * 4;  // 19.3 MB
    int2*  sep    = (int2*)w;   w += (size_t)NBK * CAP * 8;             // 25.7 MB
    int*   cursor = (int*)w;    w += 1024;
    float* a      = (float*)w;

    // sort edges into fixed-capacity 1024-row bucket slots (single fused pass)
    init_k<<<1, 128, 0, stream>>>(cursor, NBK, alpha, a, L + 1);
    fillf_k<<<GF, BS, 0, stream>>>(adj_row, adj_col, adj_val, cursor, sep, E, NBK);

    // layer 0: project to 2 dims, init out
    proj_k<<<GD(N * 32, 256), 256, 0, stream>>>(emb, node_idx, W, b, a, yA, out, N);

    // propagation layers: split-bucket SpMM -> non-atomic combine
    float* ysrc = yA;
    float* ydst = yB;
    for (int i = 0; i < L; ++i){
        spmm_k<<<NBK * KSPL, BS, 0, stream>>>(cursor, sep, ysrc, partial, NBK);
        comb_k<<<GD(N, 256), 256, 0, stream>>>(partial, a, i + 1, ydst, out,
                                               N, (i < L - 1) ? 1 : 0);
        float* tmp = ysrc; ysrc = ydst; ydst = tmp;
    }
}